// Round 9
// baseline (140.199 us; speedup 1.0000x reference)
//
#include <hip/hip_runtime.h>

// DCTProcessor: 8x8 block DCT (reference einsum: out = D @ X @ D), drop DC,
// global max of |coeff|, per-(b,c) 64-bin histogram normalized by H*W.
// Shapes: B=32, C=3, H=W=512 -> BC=96, 4096 blocks/(b,c), 393216 blocks.
//
// Fused path (one full read of x, no mag round-trip):
//   zero_kernel: 24 WGs zero d_out + done counter (plain stores; dispatch-end
//     writeback makes them visible to the next kernel's atomics).
//   dct_fused (cooperative, 768 WGs x 256 thr): each WG owns 512 blocks of
//     one (b,c). batch0 mags (f16-pairs) -> 32KB LDS; batch1 -> 32 VGPRs.
//     per-WG max -> AGENT atomic store; CUSTOM barrier (RELEASE fetch_add +
//     throttled ACQUIRE polling, s_sleep backoff, bounded) -- NOT cg::sync
//     (round-8 showed cg grid.sync costs ~70us at 768 WGs: per-WG L2
//     writeback + atomic spin across XCDs). Then global scale, replicated-LDS
//     atomic histogram, 64 exact dyadic float atomicAdds -> out.
// Fallback if cooperative launch fails: round-7 two-kernel mags-streaming.

#define NUM_BINS 64
#define HREP 16
#define NWGF 768                  // fused grid: 393216 blocks / 512
#define NWG1 1536                 // fallback pass-1 grid
#define DONE_OFF 4096             // byte offset of done counter in d_ws
#define MAGS_OFF 8192             // fallback: bytes into d_ws where mags start

typedef unsigned int uint;
typedef __fp16 fp16x2 __attribute__((ext_vector_type(2)));

__device__ __forceinline__ void load_block(const float* __restrict__ p, float* blk) {
    #pragma unroll
    for (int r = 0; r < 8; ++r) {
        float4 a = *reinterpret_cast<const float4*>(p + (size_t)r * 512);
        float4 b = *reinterpret_cast<const float4*>(p + (size_t)r * 512 + 4);
        blk[r*8+0]=a.x; blk[r*8+1]=a.y; blk[r*8+2]=a.z; blk[r*8+3]=a.w;
        blk[r*8+4]=b.x; blk[r*8+5]=b.y; blk[r*8+6]=b.z; blk[r*8+7]=b.w;
    }
}

// Symmetric 2D DCT. Dh[r*4+c] = basis[r*8+c] (left half; rows obey
// D[i][7-j] = (-1)^i D[i][j]). blk butterflied in place. Emits 63 AC |coeff|.
template <typename F>
__device__ __forceinline__ float dct_block_sym(const float* Dh, float* blk, F&& emit) {
    #pragma unroll
    for (int j = 0; j < 4; ++j)
        #pragma unroll
        for (int k = 0; k < 8; ++k) {
            float a = blk[j*8+k], b = blk[(7-j)*8+k];
            blk[j*8+k]     = a + b;
            blk[(7-j)*8+k] = a - b;
        }

    float m = 0.0f;
    #pragma unroll
    for (int i = 0; i < 8; ++i) {
        float u[8];
        #pragma unroll
        for (int k = 0; k < 8; ++k) {
            float s = 0.0f;
            #pragma unroll
            for (int j = 0; j < 4; ++j) {
                int row = (i & 1) ? (7 - j) : j;     // compile-time constant
                s = fmaf(Dh[i*4+j], blk[row*8+k], s);
            }
            u[k] = s;
        }
        #pragma unroll
        for (int l = 0; l < 4; ++l) {
            float e = 0.0f, o = 0.0f;
            #pragma unroll
            for (int k = 0; k < 4; ++k) {
                e = fmaf(u[2*k],   Dh[(2*k)*4+l],   e);
                o = fmaf(u[2*k+1], Dh[(2*k+1)*4+l], o);
            }
            float v0 = e + o;          // coeff (i, l)
            float v1 = e - o;          // coeff (i, 7-l)
            float m1 = fabsf(v1);
            m = fmaxf(m, m1);
            emit(m1);
            if (i != 0 || l != 0) {    // drop DC only
                float m0 = fabsf(v0);
                m = fmaxf(m, m0);
                emit(m0);
            }
        }
    }
    return m;
}

struct NoEmit { __device__ void operator()(float) const {} };

__device__ __forceinline__ float wave_then_wg_max(float m, float* wred) {
    #pragma unroll
    for (int off = 32; off > 0; off >>= 1)
        m = fmaxf(m, __shfl_down(m, off, 64));
    if ((threadIdx.x & 63) == 0) wred[threadIdx.x >> 6] = m;
    __syncthreads();
    return fmaxf(fmaxf(wred[0], wred[1]), fmaxf(wred[2], wred[3]));
}

// ---------------- pre-kernel: zero d_out and the barrier counter ------------
__global__ __launch_bounds__(256) void zero_kernel(float* __restrict__ out,
                                                   uint* __restrict__ done) {
    if (blockIdx.x == 0 && threadIdx.x == 0) *done = 0;
    out[blockIdx.x * 256 + threadIdx.x] = 0.0f;   // 24 WGs x 256 = 6144
}

// ======================= Fused kernel, custom barrier =======================
__global__ __launch_bounds__(256, 3) void dct_fused(
    const float* __restrict__ x, const float* __restrict__ basis,
    float* __restrict__ wgmax, uint* __restrict__ done, float* __restrict__ out)
{
    __shared__ uint  magsL[256 * 32];        // 32 KiB: batch-0 packed mags
    __shared__ uint  hist[NUM_BINS * HREP];  // 4 KiB
    __shared__ float wred[4];
    __shared__ float s_scale;

    float Dh[32];
    #pragma unroll
    for (int r = 0; r < 8; ++r)
        #pragma unroll
        for (int c = 0; c < 4; ++c)
            Dh[r*4+c] = basis[r*8+c];        // uniform const index -> s_load

    for (int i = threadIdx.x; i < NUM_BINS * HREP; i += 256) hist[i] = 0;

    const int base = blockIdx.x * 512;       // first block of this WG
    float m = 0.0f;

    // ---- batch 0 -> LDS (thread t owns magsL[q*256 + t], q=0..31) ----
    {
        int bi = base + threadIdx.x;
        int bc = bi >> 12, n = bi & 4095;
        const float* p = x + ((size_t)bc << 18) + ((size_t)((n >> 6) * 8) << 9)
                           + (size_t)((n & 63) * 8);
        float blk[64];
        load_block(p, blk);
        uint* myL = magsL + threadIdx.x;
        float flo = 0.0f;
        int   e   = 0;
        m = dct_block_sym(Dh, blk, [&](float mag) {
            if ((e & 1) == 0) flo = mag;
            else {
                fp16x2 h2 = __builtin_amdgcn_cvt_pkrtz(flo, mag);
                myL[(e >> 1) * 256] = __builtin_bit_cast(uint, h2);
            }
            ++e;                             // fully unrolled: compile-time
        });
        fp16x2 h2 = __builtin_amdgcn_cvt_pkrtz(flo, 0.0f);   // 63rd + dead pad
        myL[31 * 256] = __builtin_bit_cast(uint, h2);
    }

    // ---- batch 1 -> VGPRs ----
    uint magR[32];
    {
        int bi = base + 256 + threadIdx.x;
        int bc = bi >> 12, n = bi & 4095;
        const float* p = x + ((size_t)bc << 18) + ((size_t)((n >> 6) * 8) << 9)
                           + (size_t)((n & 63) * 8);
        float blk[64];
        load_block(p, blk);
        float flo = 0.0f;
        int   e   = 0;
        float m2 = dct_block_sym(Dh, blk, [&](float mag) {
            if ((e & 1) == 0) flo = mag;
            else {
                fp16x2 h2 = __builtin_amdgcn_cvt_pkrtz(flo, mag);
                magR[e >> 1] = __builtin_bit_cast(uint, h2);
            }
            ++e;
        });
        fp16x2 h2 = __builtin_amdgcn_cvt_pkrtz(flo, 0.0f);
        magR[31] = __builtin_bit_cast(uint, h2);
        m = fmaxf(m, m2);
    }

    // ---- per-WG max -> global (AGENT atomic store: XCD-coherence-proof) ----
    float wm = wave_then_wg_max(m, wred);
    if (threadIdx.x == 0)
        __hip_atomic_store(&wgmax[blockIdx.x], wm,
                           __ATOMIC_RELAXED, __HIP_MEMORY_SCOPE_AGENT);

    // ---- custom grid barrier: one RELEASE add, throttled ACQUIRE polling ----
    if (threadIdx.x == 0) {
        __hip_atomic_fetch_add(done, 1u, __ATOMIC_RELEASE,
                               __HIP_MEMORY_SCOPE_AGENT);
        // bounded spin (no hang even if something goes wrong); ~0.85us backoff
        for (int spin = 0; spin < (1 << 20); ++spin) {
            if (__hip_atomic_load(done, __ATOMIC_ACQUIRE,
                                  __HIP_MEMORY_SCOPE_AGENT) >= NWGF) break;
            __builtin_amdgcn_s_sleep(32);
        }
    }
    __syncthreads();

    // ---- global scale from the 768 maxima (AGENT loads) ----
    {
        float g = 0.0f;
        #pragma unroll
        for (int r = 0; r < 3; ++r)
            g = fmaxf(g, __hip_atomic_load(&wgmax[threadIdx.x + r * 256],
                                           __ATOMIC_RELAXED,
                                           __HIP_MEMORY_SCOPE_AGENT));
        #pragma unroll
        for (int off = 32; off > 0; off >>= 1)
            g = fmaxf(g, __shfl_down(g, off, 64));
        if ((threadIdx.x & 63) == 0) wred[threadIdx.x >> 6] = g;
        __syncthreads();
        if (threadIdx.x == 0) {
            float mm = fmaxf(fmaxf(wred[0], wred[1]), fmaxf(wred[2], wred[3]));
            s_scale = (float)NUM_BINS / (mm * 1.1f);
        }
        __syncthreads();
    }
    float scale = s_scale;
    int   sub   = threadIdx.x & (HREP - 1);

    // ---- bin batch 1 (VGPR): 31 full dwords + low half of dword 31 ----
    #pragma unroll
    for (int q = 0; q < 32; ++q) {
        fp16x2 h2 = __builtin_bit_cast(fp16x2, magR[q]);
        float f0 = (float)h2[0];
        int b0 = min((int)(f0 * scale), NUM_BINS - 1);
        atomicAdd(&hist[b0 * HREP + sub], 1u);
        if (q < 31) {
            float f1 = (float)h2[1];
            int b1 = min((int)(f1 * scale), NUM_BINS - 1);
            atomicAdd(&hist[b1 * HREP + sub], 1u);
        }
    }
    // ---- bin batch 0 (LDS) ----
    {
        const uint* myL = magsL + threadIdx.x;
        #pragma unroll
        for (int q = 0; q < 32; ++q) {
            fp16x2 h2 = __builtin_bit_cast(fp16x2, myL[q * 256]);
            float f0 = (float)h2[0];
            int b0 = min((int)(f0 * scale), NUM_BINS - 1);
            atomicAdd(&hist[b0 * HREP + sub], 1u);
            if (q < 31) {
                float f1 = (float)h2[1];
                int b1 = min((int)(f1 * scale), NUM_BINS - 1);
                atomicAdd(&hist[b1 * HREP + sub], 1u);
            }
        }
    }
    __syncthreads();

    if (threadIdx.x < NUM_BINS) {
        uint c = 0;
        #pragma unroll
        for (int r = 0; r < HREP; ++r) c += hist[threadIdx.x * HREP + r];
        int bc = blockIdx.x >> 3;               // 8 WGs per (b,c)
        // counts <= 32256 exact; /2^18 dyadic -> 8-way float atomic sum exact
        atomicAdd(&out[bc * NUM_BINS + threadIdx.x], (float)c * (1.0f / 262144.0f));
    }
}

// ======================= Fallback: round-7 two-kernel =======================
template <bool WRITE_MAGS>
__global__ __launch_bounds__(256) void dct_max_kernel(
    const float* __restrict__ x, const float* __restrict__ basis,
    float* __restrict__ wgmax, uint* __restrict__ mags, float* __restrict__ out)
{
    __shared__ float wred[4];
    float Dh[32];
    #pragma unroll
    for (int r = 0; r < 8; ++r)
        #pragma unroll
        for (int c = 0; c < 4; ++c)
            Dh[r*4+c] = basis[r*8+c];

    if (blockIdx.x < 24) out[blockIdx.x * 256 + threadIdx.x] = 0.0f;

    int tid = blockIdx.x * 256 + threadIdx.x;
    int bc  = tid >> 12, n = tid & 4095;
    const float* p = x + ((size_t)bc << 18) + ((size_t)((n >> 6) * 8) << 9)
                       + (size_t)((n & 63) * 8);
    float blk[64];
    load_block(p, blk);

    float m;
    if (WRITE_MAGS) {
        uint* wbase = mags + (size_t)(tid >> 6) * 2048 + (tid & 63);
        float flo = 0.0f;
        int   e   = 0;
        m = dct_block_sym(Dh, blk, [&](float mag) {
            if ((e & 1) == 0) flo = mag;
            else {
                fp16x2 h2 = __builtin_amdgcn_cvt_pkrtz(flo, mag);
                wbase[(e >> 1) * 64] = __builtin_bit_cast(uint, h2);
            }
            ++e;
        });
        fp16x2 h2 = __builtin_amdgcn_cvt_pkrtz(flo, -__builtin_inff());
        wbase[31 * 64] = __builtin_bit_cast(uint, h2);
    } else {
        m = dct_block_sym(Dh, blk, NoEmit{});
    }

    float wm = wave_then_wg_max(m, wred);
    if (threadIdx.x == 0) wgmax[blockIdx.x] = wm;
}

__device__ __forceinline__ float reduce_scale(const float* __restrict__ wgmax,
                                              float* wred, float* s_scale) {
    float m = 0.0f;
    for (int i = threadIdx.x; i < NWG1; i += 256) m = fmaxf(m, wgmax[i]);
    float wm = wave_then_wg_max(m, wred);
    if (threadIdx.x == 0) *s_scale = (float)NUM_BINS / (wm * 1.1f);
    __syncthreads();
    return *s_scale;
}

__global__ __launch_bounds__(256) void dct_hist_frommags(
    const uint* __restrict__ mags, const float* __restrict__ wgmax,
    float* __restrict__ out)
{
    __shared__ uint hist[NUM_BINS * HREP];
    __shared__ float wred[4];
    __shared__ float s_scale;
    for (int i = threadIdx.x; i < NUM_BINS * HREP; i += 256) hist[i] = 0;

    float scale = reduce_scale(wgmax, wred, &s_scale);
    int   sub   = threadIdx.x & (HREP - 1);
    int   bc    = blockIdx.x >> 4;

    const uint* src = mags + (size_t)blockIdx.x * 8192 + threadIdx.x * 4;
    #pragma unroll
    for (int j = 0; j < 8; ++j) {
        uint4 v = *reinterpret_cast<const uint4*>(src + (size_t)j * 1024);
        uint w[4] = {v.x, v.y, v.z, v.w};
        #pragma unroll
        for (int u = 0; u < 4; ++u) {
            fp16x2 h2 = __builtin_bit_cast(fp16x2, w[u]);
            float f0 = (float)h2[0];
            float f1 = (float)h2[1];
            int b0 = min((int)(fmaxf(f0, 0.0f) * scale), NUM_BINS - 1);
            int b1 = min((int)(fmaxf(f1, 0.0f) * scale), NUM_BINS - 1);
            if (f0 >= 0.0f) atomicAdd(&hist[b0 * HREP + sub], 1u);
            if (f1 >= 0.0f) atomicAdd(&hist[b1 * HREP + sub], 1u);
        }
    }
    __syncthreads();

    if (threadIdx.x < NUM_BINS) {
        uint c = 0;
        #pragma unroll
        for (int r = 0; r < HREP; ++r) c += hist[threadIdx.x * HREP + r];
        atomicAdd(&out[bc * NUM_BINS + threadIdx.x], (float)c * (1.0f / 262144.0f));
    }
}

__global__ __launch_bounds__(256) void dct_hist_recompute(
    const float* __restrict__ x, const float* __restrict__ basis,
    const float* __restrict__ wgmax, float* __restrict__ out)
{
    __shared__ uint hist[NUM_BINS * HREP];
    __shared__ float wred[4];
    __shared__ float s_scale;
    float Dh[32];
    #pragma unroll
    for (int r = 0; r < 8; ++r)
        #pragma unroll
        for (int c = 0; c < 4; ++c)
            Dh[r*4+c] = basis[r*8+c];
    for (int i = threadIdx.x; i < NUM_BINS * HREP; i += 256) hist[i] = 0;

    float scale = reduce_scale(wgmax, wred, &s_scale);
    int   sub   = threadIdx.x & (HREP - 1);
    int   bc    = blockIdx.x >> 4;
    int   n     = (blockIdx.x & 15) * 256 + threadIdx.x;
    const float* p = x + ((size_t)bc << 18) + ((size_t)((n >> 6) * 8) << 9)
                       + (size_t)((n & 63) * 8);
    float blk[64];
    load_block(p, blk);
    dct_block_sym(Dh, blk, [&](float mag) {
        int bin = min((int)(mag * scale), NUM_BINS - 1);
        atomicAdd(&hist[bin * HREP + sub], 1u);
    });
    __syncthreads();

    if (threadIdx.x < NUM_BINS) {
        uint c = 0;
        #pragma unroll
        for (int r = 0; r < HREP; ++r) c += hist[threadIdx.x * HREP + r];
        atomicAdd(&out[bc * NUM_BINS + threadIdx.x], (float)c * (1.0f / 262144.0f));
    }
}

extern "C" void kernel_launch(void* const* d_in, const int* in_sizes, int n_in,
                              void* d_out, int out_size, void* d_ws, size_t ws_size,
                              hipStream_t stream) {
    const float* x     = (const float*)d_in[0];
    const float* basis = (const float*)d_in[1];
    float* out         = (float*)d_out;
    float* wgmax       = (float*)d_ws;
    uint*  done        = (uint*)((char*)d_ws + DONE_OFF);
    uint*  mags        = (uint*)((char*)d_ws + MAGS_OFF);

    zero_kernel<<<24, 256, 0, stream>>>(out, done);

    void* args[] = {(void*)&x, (void*)&basis, (void*)&wgmax, (void*)&done,
                    (void*)&out};
    hipError_t err = hipLaunchCooperativeKernel(
        (const void*)dct_fused, dim3(NWGF), dim3(256), args, 0, stream);
    if (err == hipSuccess) return;
    (void)hipGetLastError();   // clear sticky error; fall back deterministically

    const size_t need = (size_t)MAGS_OFF + (size_t)NWG1 * 256 * 128;  // 50.34 MB
    if (ws_size >= need) {
        dct_max_kernel<true><<<NWG1, 256, 0, stream>>>(x, basis, wgmax, mags, out);
        dct_hist_frommags<<<NWG1, 256, 0, stream>>>(mags, wgmax, out);
    } else {
        dct_max_kernel<false><<<NWG1, 256, 0, stream>>>(x, basis, wgmax, mags, out);
        dct_hist_recompute<<<NWG1, 256, 0, stream>>>(x, basis, wgmax, out);
    }
}

// Round 10
// 39.920 us; speedup vs baseline: 3.5120x; 3.5120x over previous
//
#include <hip/hip_runtime.h>

// DCTProcessor: 8x8 block DCT (reference einsum: out = D @ X @ D), drop DC,
// global max of |coeff|, per-(b,c) 64-bin histogram normalized by H*W.
// Shapes: B=32, C=3, H=W=512 -> BC=96, 4096 blocks/(b,c), 393216 blocks.
//
// Two-kernel structure (the dispatch boundary is the cheap grid barrier;
// rounds 8/9 proved in-kernel grid sync costs ~100us here):
//  k1: one 8x8 block/thread, symmetric fast DCT (D half-matrix in SGPRs),
//      per-WG max -> d_ws; streams 63 AC |coeff| as packed f16 pairs via
//      8 coalesced dwordx4 stores/thread (bag layout -- k2 ignores order).
//      Slot 64 = f16 -inf pad. First 24 WGs zero d_out.
//  k2: reads mags (L2/L3-hot uint4), reduces 1536 partial maxima, bins 64
//      halves/thread gated on >=0 (pad reject), 32-replica LDS atomic hist
//      (replica=lane&31 -> bank==lane, zero cross-lane bank conflicts),
//      64 exact dyadic float atomicAdds per WG.
// Fallback (ws too small): recompute-DCT histogram kernel.

#define NUM_BINS 64
#define HREP 32
#define NWG1 1536                 // 393216 blocks / 256 threads
#define MAGS_OFF 8192             // bytes into d_ws where mags start

typedef unsigned int uint;
typedef __fp16 fp16x2 __attribute__((ext_vector_type(2)));

__device__ __forceinline__ void load_block(const float* __restrict__ p, float* blk) {
    #pragma unroll
    for (int r = 0; r < 8; ++r) {
        float4 a = *reinterpret_cast<const float4*>(p + (size_t)r * 512);
        float4 b = *reinterpret_cast<const float4*>(p + (size_t)r * 512 + 4);
        blk[r*8+0]=a.x; blk[r*8+1]=a.y; blk[r*8+2]=a.z; blk[r*8+3]=a.w;
        blk[r*8+4]=b.x; blk[r*8+5]=b.y; blk[r*8+6]=b.z; blk[r*8+7]=b.w;
    }
}

// Symmetric 2D DCT. Dh[r*4+c] = basis[r*8+c] (left half; rows obey
// D[i][7-j] = (-1)^i D[i][j]). blk butterflied in place. Emits 63 AC |coeff|.
template <typename F>
__device__ __forceinline__ float dct_block_sym(const float* Dh, float* blk, F&& emit) {
    #pragma unroll
    for (int j = 0; j < 4; ++j)
        #pragma unroll
        for (int k = 0; k < 8; ++k) {
            float a = blk[j*8+k], b = blk[(7-j)*8+k];
            blk[j*8+k]     = a + b;
            blk[(7-j)*8+k] = a - b;
        }

    float m = 0.0f;
    #pragma unroll
    for (int i = 0; i < 8; ++i) {
        float u[8];
        #pragma unroll
        for (int k = 0; k < 8; ++k) {
            float s = 0.0f;
            #pragma unroll
            for (int j = 0; j < 4; ++j) {
                int row = (i & 1) ? (7 - j) : j;     // compile-time constant
                s = fmaf(Dh[i*4+j], blk[row*8+k], s);
            }
            u[k] = s;
        }
        #pragma unroll
        for (int l = 0; l < 4; ++l) {
            float e = 0.0f, o = 0.0f;
            #pragma unroll
            for (int k = 0; k < 4; ++k) {
                e = fmaf(u[2*k],   Dh[(2*k)*4+l],   e);
                o = fmaf(u[2*k+1], Dh[(2*k+1)*4+l], o);
            }
            float v0 = e + o;          // coeff (i, l)
            float v1 = e - o;          // coeff (i, 7-l)
            float m1 = fabsf(v1);
            m = fmaxf(m, m1);
            emit(m1);
            if (i != 0 || l != 0) {    // drop DC only
                float m0 = fabsf(v0);
                m = fmaxf(m, m0);
                emit(m0);
            }
        }
    }
    return m;
}

struct NoEmit { __device__ void operator()(float) const {} };

__device__ __forceinline__ float wave_then_wg_max(float m, float* wred) {
    #pragma unroll
    for (int off = 32; off > 0; off >>= 1)
        m = fmaxf(m, __shfl_down(m, off, 64));
    if ((threadIdx.x & 63) == 0) wred[threadIdx.x >> 6] = m;
    __syncthreads();
    return fmaxf(fmaxf(wred[0], wred[1]), fmaxf(wred[2], wred[3]));
}

// ---------------- Pass 1: max + stream packed f16 mags (dwordx4) -----------
template <bool WRITE_MAGS>
__global__ __launch_bounds__(256) void dct_max_kernel(
    const float* __restrict__ x, const float* __restrict__ basis,
    float* __restrict__ wgmax, uint* __restrict__ mags, float* __restrict__ out)
{
    __shared__ float wred[4];
    float Dh[32];
    #pragma unroll
    for (int r = 0; r < 8; ++r)
        #pragma unroll
        for (int c = 0; c < 4; ++c)
            Dh[r*4+c] = basis[r*8+c];     // uniform const index -> s_load

    if (blockIdx.x < 24) out[blockIdx.x * 256 + threadIdx.x] = 0.0f;

    int tid = blockIdx.x * 256 + threadIdx.x;   // one 8x8 block per thread
    int bc  = tid >> 12, n = tid & 4095;
    const float* p = x + ((size_t)bc << 18) + ((size_t)((n >> 6) * 8) << 9)
                       + (size_t)((n & 63) * 8);
    float blk[64];
    load_block(p, blk);

    float m;
    if (WRITE_MAGS) {
        // bag layout: wave w owns dwords [w*2048, (w+1)*2048); lane l's slot s
        // is the uint4 at dword w*2048 + s*256 + l*4  -> each dwordx4 store
        // covers 256 contiguous dwords (1 KB) per wave: fully coalesced.
        uint* wbase = mags + (size_t)(tid >> 6) * 2048 + (size_t)(tid & 63) * 4;
        uint  buf[4];
        float flo = 0.0f;
        int   e   = 0;
        m = dct_block_sym(Dh, blk, [&](float mag) {
            if ((e & 1) == 0) flo = mag;
            else {
                int p2 = e >> 1;                 // compile-time (full unroll)
                fp16x2 h2 = __builtin_amdgcn_cvt_pkrtz(flo, mag);
                buf[p2 & 3] = __builtin_bit_cast(uint, h2);
                if ((p2 & 3) == 3)
                    *reinterpret_cast<uint4*>(wbase + (p2 >> 2) * 256) =
                        uint4{buf[0], buf[1], buf[2], buf[3]};
            }
            ++e;
        });
        // 63 emits: pair 31 = (emit#62, -inf pad) completes slot 7
        fp16x2 h2 = __builtin_amdgcn_cvt_pkrtz(flo, -__builtin_inff());
        buf[3] = __builtin_bit_cast(uint, h2);
        *reinterpret_cast<uint4*>(wbase + 7 * 256) =
            uint4{buf[0], buf[1], buf[2], buf[3]};
    } else {
        m = dct_block_sym(Dh, blk, NoEmit{});
    }

    float wm = wave_then_wg_max(m, wred);
    if (threadIdx.x == 0) wgmax[blockIdx.x] = wm;
}

__device__ __forceinline__ float reduce_scale(const float* __restrict__ wgmax,
                                              float* wred, float* s_scale) {
    float m = 0.0f;
    for (int i = threadIdx.x; i < NWG1; i += 256) m = fmaxf(m, wgmax[i]);
    float wm = wave_then_wg_max(m, wred);
    if (threadIdx.x == 0) *s_scale = (float)NUM_BINS / (wm * 1.1f);
    __syncthreads();
    return *s_scale;
}

// ---------------- Pass 2: histogram from packed f16 mags ----------------
__global__ __launch_bounds__(256) void dct_hist_frommags(
    const uint* __restrict__ mags, const float* __restrict__ wgmax,
    float* __restrict__ out)
{
    __shared__ uint hist[NUM_BINS * HREP];   // 8 KiB
    __shared__ float wred[4];
    __shared__ float s_scale;
    for (int i = threadIdx.x; i < NUM_BINS * HREP; i += 256) hist[i] = 0;

    float scale = reduce_scale(wgmax, wred, &s_scale);
    int   sub   = threadIdx.x & (HREP - 1);   // replica = lane&31 -> bank==lane
    int   bc    = blockIdx.x >> 4;            // 16 WGs per (b,c)

    // this WG consumes dwords [blockIdx.x*8192, +8192): 8 coalesced uint4 loads
    const uint* src = mags + (size_t)blockIdx.x * 8192 + threadIdx.x * 4;
    #pragma unroll
    for (int j = 0; j < 8; ++j) {
        uint4 v = *reinterpret_cast<const uint4*>(src + (size_t)j * 1024);
        uint w[4] = {v.x, v.y, v.z, v.w};
        #pragma unroll
        for (int u = 0; u < 4; ++u) {
            fp16x2 h2 = __builtin_bit_cast(fp16x2, w[u]);
            float f0 = (float)h2[0];
            float f1 = (float)h2[1];
            // pad = -inf: gate on >= 0 (all real mags are >= 0)
            int b0 = min((int)(fmaxf(f0, 0.0f) * scale), NUM_BINS - 1);
            int b1 = min((int)(fmaxf(f1, 0.0f) * scale), NUM_BINS - 1);
            if (f0 >= 0.0f) atomicAdd(&hist[b0 * HREP + sub], 1u);
            if (f1 >= 0.0f) atomicAdd(&hist[b1 * HREP + sub], 1u);
        }
    }
    __syncthreads();

    if (threadIdx.x < NUM_BINS) {
        uint c = 0;
        #pragma unroll
        for (int r = 0; r < HREP; ++r) c += hist[threadIdx.x * HREP + r];
        // counts <= 2^18, /2^18 dyadic -> float atomic sum exact + deterministic
        atomicAdd(&out[bc * NUM_BINS + threadIdx.x], (float)c * (1.0f / 262144.0f));
    }
}

// ---------------- Fallback pass 2: recompute DCT ----------------
__global__ __launch_bounds__(256) void dct_hist_recompute(
    const float* __restrict__ x, const float* __restrict__ basis,
    const float* __restrict__ wgmax, float* __restrict__ out)
{
    __shared__ uint hist[NUM_BINS * HREP];
    __shared__ float wred[4];
    __shared__ float s_scale;
    float Dh[32];
    #pragma unroll
    for (int r = 0; r < 8; ++r)
        #pragma unroll
        for (int c = 0; c < 4; ++c)
            Dh[r*4+c] = basis[r*8+c];
    for (int i = threadIdx.x; i < NUM_BINS * HREP; i += 256) hist[i] = 0;

    float scale = reduce_scale(wgmax, wred, &s_scale);
    int   sub   = threadIdx.x & (HREP - 1);
    int   bc    = blockIdx.x >> 4;
    int   n     = (blockIdx.x & 15) * 256 + threadIdx.x;
    const float* p = x + ((size_t)bc << 18) + ((size_t)((n >> 6) * 8) << 9)
                       + (size_t)((n & 63) * 8);
    float blk[64];
    load_block(p, blk);
    dct_block_sym(Dh, blk, [&](float mag) {
        int bin = min((int)(mag * scale), NUM_BINS - 1);
        atomicAdd(&hist[bin * HREP + sub], 1u);
    });
    __syncthreads();

    if (threadIdx.x < NUM_BINS) {
        uint c = 0;
        #pragma unroll
        for (int r = 0; r < HREP; ++r) c += hist[threadIdx.x * HREP + r];
        atomicAdd(&out[bc * NUM_BINS + threadIdx.x], (float)c * (1.0f / 262144.0f));
    }
}

extern "C" void kernel_launch(void* const* d_in, const int* in_sizes, int n_in,
                              void* d_out, int out_size, void* d_ws, size_t ws_size,
                              hipStream_t stream) {
    const float* x     = (const float*)d_in[0];
    const float* basis = (const float*)d_in[1];
    float* out         = (float*)d_out;
    float* wgmax       = (float*)d_ws;
    uint*  mags        = (uint*)((char*)d_ws + MAGS_OFF);

    const size_t need = (size_t)MAGS_OFF + (size_t)NWG1 * 256 * 128;  // 50.34 MB
    if (ws_size >= need) {
        dct_max_kernel<true><<<NWG1, 256, 0, stream>>>(x, basis, wgmax, mags, out);
        dct_hist_frommags<<<NWG1, 256, 0, stream>>>(mags, wgmax, out);
    } else {
        dct_max_kernel<false><<<NWG1, 256, 0, stream>>>(x, basis, wgmax, mags, out);
        dct_hist_recompute<<<NWG1, 256, 0, stream>>>(x, basis, wgmax, out);
    }
}

// Round 12
// 39.332 us; speedup vs baseline: 3.5645x; 1.0149x over previous
//
#include <hip/hip_runtime.h>

// DCTProcessor: 8x8 block DCT (reference einsum: out = D @ X @ D), drop DC,
// global max of |coeff|, per-(b,c) 64-bin histogram normalized by H*W.
// Shapes: B=32, C=3, H=W=512 -> BC=96, 4096 blocks/(b,c), 393216 blocks.
//
// ROUND-7 configuration (best passing: 39.2us). Two-kernel structure; the
// dispatch boundary is the grid barrier (in-kernel grid sync measured ~100us
// at 768 WGs on this chip -- rounds 8/9). Memory-bound at ~196MB total
// traffic (96 x-read + 50 mag-write + 50 mag-read) ~= 31us floor at 6.3TB/s.
// NOTE: do NOT use __builtin_nontemporal_* on the mag buffer -- round 11
// showed nt hints break cross-dispatch store->load visibility here (704
// misplaced counts, deterministic).
//
//  k1: one 8x8 block/thread, symmetric fast DCT (D half-matrix in SGPRs),
//      per-WG max -> d_ws; streams 63 AC |coeff| as packed f16 pairs (RTZ)
//      in lane-coalesced dword stores (bag layout -- k2 ignores order).
//      Slot 64 = f16 -inf pad. First 24 WGs zero d_out.
//  k2: uint4 mag loads (L2/L3-hot), reduces 1536 partial maxima, bins 64
//      halves/thread gated on >=0 (pad reject), 16-replica LDS atomic hist,
//      64 exact dyadic float atomicAdds per WG.
// Fallback (ws too small): recompute-DCT histogram kernel.

#define NUM_BINS 64
#define HREP 16
#define NWG1 1536                 // 393216 blocks / 256 threads
#define MAGS_OFF 8192             // bytes into d_ws where mags start

typedef unsigned int uint;
typedef __fp16 fp16x2 __attribute__((ext_vector_type(2)));

__device__ __forceinline__ void load_block(const float* __restrict__ p, float* blk) {
    #pragma unroll
    for (int r = 0; r < 8; ++r) {
        float4 a = *reinterpret_cast<const float4*>(p + (size_t)r * 512);
        float4 b = *reinterpret_cast<const float4*>(p + (size_t)r * 512 + 4);
        blk[r*8+0]=a.x; blk[r*8+1]=a.y; blk[r*8+2]=a.z; blk[r*8+3]=a.w;
        blk[r*8+4]=b.x; blk[r*8+5]=b.y; blk[r*8+6]=b.z; blk[r*8+7]=b.w;
    }
}

// Symmetric 2D DCT. Dh[r*4+c] = basis[r*8+c] (left half; rows obey
// D[i][7-j] = (-1)^i D[i][j]). blk butterflied in place. Emits 63 AC |coeff|.
template <typename F>
__device__ __forceinline__ float dct_block_sym(const float* Dh, float* blk, F&& emit) {
    #pragma unroll
    for (int j = 0; j < 4; ++j)
        #pragma unroll
        for (int k = 0; k < 8; ++k) {
            float a = blk[j*8+k], b = blk[(7-j)*8+k];
            blk[j*8+k]     = a + b;
            blk[(7-j)*8+k] = a - b;
        }

    float m = 0.0f;
    #pragma unroll
    for (int i = 0; i < 8; ++i) {
        float u[8];
        #pragma unroll
        for (int k = 0; k < 8; ++k) {
            float s = 0.0f;
            #pragma unroll
            for (int j = 0; j < 4; ++j) {
                int row = (i & 1) ? (7 - j) : j;     // compile-time constant
                s = fmaf(Dh[i*4+j], blk[row*8+k], s);
            }
            u[k] = s;
        }
        #pragma unroll
        for (int l = 0; l < 4; ++l) {
            float e = 0.0f, o = 0.0f;
            #pragma unroll
            for (int k = 0; k < 4; ++k) {
                e = fmaf(u[2*k],   Dh[(2*k)*4+l],   e);
                o = fmaf(u[2*k+1], Dh[(2*k+1)*4+l], o);
            }
            float v0 = e + o;          // coeff (i, l)
            float v1 = e - o;          // coeff (i, 7-l)
            float m1 = fabsf(v1);
            m = fmaxf(m, m1);
            emit(m1);
            if (i != 0 || l != 0) {    // drop DC only
                float m0 = fabsf(v0);
                m = fmaxf(m, m0);
                emit(m0);
            }
        }
    }
    return m;
}

struct NoEmit { __device__ void operator()(float) const {} };

__device__ __forceinline__ float wave_then_wg_max(float m, float* wred) {
    #pragma unroll
    for (int off = 32; off > 0; off >>= 1)
        m = fmaxf(m, __shfl_down(m, off, 64));
    if ((threadIdx.x & 63) == 0) wred[threadIdx.x >> 6] = m;
    __syncthreads();
    return fmaxf(fmaxf(wred[0], wred[1]), fmaxf(wred[2], wred[3]));
}

// ---------------- Pass 1: max + stream packed f16 mags --------
template <bool WRITE_MAGS>
__global__ __launch_bounds__(256) void dct_max_kernel(
    const float* __restrict__ x, const float* __restrict__ basis,
    float* __restrict__ wgmax, uint* __restrict__ mags, float* __restrict__ out)
{
    __shared__ float wred[4];
    float Dh[32];
    #pragma unroll
    for (int r = 0; r < 8; ++r)
        #pragma unroll
        for (int c = 0; c < 4; ++c)
            Dh[r*4+c] = basis[r*8+c];     // uniform const index -> s_load

    if (blockIdx.x < 24) out[blockIdx.x * 256 + threadIdx.x] = 0.0f;

    int tid = blockIdx.x * 256 + threadIdx.x;   // one 8x8 block per thread
    int bc  = tid >> 12, n = tid & 4095;
    const float* p = x + ((size_t)bc << 18) + ((size_t)((n >> 6) * 8) << 9)
                       + (size_t)((n & 63) * 8);
    float blk[64];
    load_block(p, blk);

    float m;
    if (WRITE_MAGS) {
        // bag layout: wave w owns dwords [w*2048, (w+1)*2048); pair q of
        // lane l at w*2048 + q*64 + l -> each store instruction covers 64
        // consecutive dwords (256B contiguous per wave): fully coalesced.
        uint* wbase = mags + (size_t)(tid >> 6) * 2048 + (tid & 63);
        float flo = 0.0f;
        int   e   = 0;
        m = dct_block_sym(Dh, blk, [&](float mag) {
            if ((e & 1) == 0) flo = mag;
            else {
                fp16x2 h2 = __builtin_amdgcn_cvt_pkrtz(flo, mag);
                wbase[(e >> 1) * 64] = __builtin_bit_cast(uint, h2);
            }
            ++e;                                   // fully unrolled: e is const
        });
        // 63 emits -> last pair: (emit#62, -inf pad)
        fp16x2 h2 = __builtin_amdgcn_cvt_pkrtz(flo, -__builtin_inff());
        wbase[31 * 64] = __builtin_bit_cast(uint, h2);
    } else {
        m = dct_block_sym(Dh, blk, NoEmit{});
    }

    float wm = wave_then_wg_max(m, wred);
    if (threadIdx.x == 0) wgmax[blockIdx.x] = wm;
}

__device__ __forceinline__ float reduce_scale(const float* __restrict__ wgmax,
                                              float* wred, float* s_scale) {
    float m = 0.0f;
    for (int i = threadIdx.x; i < NWG1; i += 256) m = fmaxf(m, wgmax[i]);
    float wm = wave_then_wg_max(m, wred);
    if (threadIdx.x == 0) *s_scale = (float)NUM_BINS / (wm * 1.1f);
    __syncthreads();
    return *s_scale;
}

// ---------------- Pass 2: histogram from packed f16 mags ----------------
__global__ __launch_bounds__(256) void dct_hist_frommags(
    const uint* __restrict__ mags, const float* __restrict__ wgmax,
    float* __restrict__ out)
{
    __shared__ uint hist[NUM_BINS * HREP];   // 4 KiB
    __shared__ float wred[4];
    __shared__ float s_scale;
    for (int i = threadIdx.x; i < NUM_BINS * HREP; i += 256) hist[i] = 0;

    float scale = reduce_scale(wgmax, wred, &s_scale);
    int   sub   = threadIdx.x & (HREP - 1);
    int   bc    = blockIdx.x >> 4;            // 16 WGs per (b,c)

    // this WG consumes dwords [blockIdx.x*8192, +8192): 8 coalesced uint4 loads
    const uint* src = mags + (size_t)blockIdx.x * 8192 + threadIdx.x * 4;
    #pragma unroll
    for (int j = 0; j < 8; ++j) {
        uint4 v = *reinterpret_cast<const uint4*>(src + (size_t)j * 1024);
        uint w[4] = {v.x, v.y, v.z, v.w};
        #pragma unroll
        for (int u = 0; u < 4; ++u) {
            fp16x2 h2 = __builtin_bit_cast(fp16x2, w[u]);
            float f0 = (float)h2[0];
            float f1 = (float)h2[1];
            // pad = -inf: gate on >= 0 (all real mags are >= 0)
            int b0 = min((int)(fmaxf(f0, 0.0f) * scale), NUM_BINS - 1);
            int b1 = min((int)(fmaxf(f1, 0.0f) * scale), NUM_BINS - 1);
            if (f0 >= 0.0f) atomicAdd(&hist[b0 * HREP + sub], 1u);
            if (f1 >= 0.0f) atomicAdd(&hist[b1 * HREP + sub], 1u);
        }
    }
    __syncthreads();

    if (threadIdx.x < NUM_BINS) {
        uint c = 0;
        #pragma unroll
        for (int r = 0; r < HREP; ++r) c += hist[threadIdx.x * HREP + r];
        // counts <= 2^18, /2^18 dyadic -> float atomic sum exact + deterministic
        atomicAdd(&out[bc * NUM_BINS + threadIdx.x], (float)c * (1.0f / 262144.0f));
    }
}

// ---------------- Fallback pass 2: recompute DCT ----------------
__global__ __launch_bounds__(256) void dct_hist_recompute(
    const float* __restrict__ x, const float* __restrict__ basis,
    const float* __restrict__ wgmax, float* __restrict__ out)
{
    __shared__ uint hist[NUM_BINS * HREP];
    __shared__ float wred[4];
    __shared__ float s_scale;
    float Dh[32];
    #pragma unroll
    for (int r = 0; r < 8; ++r)
        #pragma unroll
        for (int c = 0; c < 4; ++c)
            Dh[r*4+c] = basis[r*8+c];
    for (int i = threadIdx.x; i < NUM_BINS * HREP; i += 256) hist[i] = 0;

    float scale = reduce_scale(wgmax, wred, &s_scale);
    int   sub   = threadIdx.x & (HREP - 1);
    int   bc    = blockIdx.x >> 4;
    int   n     = (blockIdx.x & 15) * 256 + threadIdx.x;
    const float* p = x + ((size_t)bc << 18) + ((size_t)((n >> 6) * 8) << 9)
                       + (size_t)((n & 63) * 8);
    float blk[64];
    load_block(p, blk);
    dct_block_sym(Dh, blk, [&](float mag) {
        int bin = min((int)(mag * scale), NUM_BINS - 1);
        atomicAdd(&hist[bin * HREP + sub], 1u);
    });
    __syncthreads();

    if (threadIdx.x < NUM_BINS) {
        uint c = 0;
        #pragma unroll
        for (int r = 0; r < HREP; ++r) c += hist[threadIdx.x * HREP + r];
        atomicAdd(&out[bc * NUM_BINS + threadIdx.x], (float)c * (1.0f / 262144.0f));
    }
}

extern "C" void kernel_launch(void* const* d_in, const int* in_sizes, int n_in,
                              void* d_out, int out_size, void* d_ws, size_t ws_size,
                              hipStream_t stream) {
    const float* x     = (const float*)d_in[0];
    const float* basis = (const float*)d_in[1];
    float* out         = (float*)d_out;
    float* wgmax       = (float*)d_ws;
    uint*  mags        = (uint*)((char*)d_ws + MAGS_OFF);

    const size_t need = (size_t)MAGS_OFF + (size_t)NWG1 * 256 * 128;  // 50.34 MB
    if (ws_size >= need) {
        dct_max_kernel<true><<<NWG1, 256, 0, stream>>>(x, basis, wgmax, mags, out);
        dct_hist_frommags<<<NWG1, 256, 0, stream>>>(mags, wgmax, out);
    } else {
        dct_max_kernel<false><<<NWG1, 256, 0, stream>>>(x, basis, wgmax, mags, out);
        dct_hist_recompute<<<NWG1, 256, 0, stream>>>(x, basis, wgmax, out);
    }
}

// Round 13
// 39.294 us; speedup vs baseline: 3.5680x; 1.0010x over previous
//
#include <hip/hip_runtime.h>

// DCTProcessor: 8x8 block DCT (reference einsum: out = D @ X @ D), drop DC,
// global max of |coeff|, per-(b,c) 64-bin histogram normalized by H*W.
// Shapes: B=32, C=3, H=W=512 -> BC=96, 4096 blocks/(b,c), 393216 blocks.
//
// ROUND-7 configuration (best passing: 39.2us). Two-kernel structure; the
// dispatch boundary is the grid barrier (in-kernel grid sync measured ~100us
// at 768 WGs on this chip -- rounds 8/9). Memory-bound at ~196MB total
// traffic (96 x-read + 50 mag-write + 50 mag-read) ~= 31us floor at 6.3TB/s.
// NOTE: do NOT use __builtin_nontemporal_* on the mag buffer -- round 11
// showed nt hints break cross-dispatch store->load visibility here (704
// misplaced counts, deterministic).
//
//  k1: one 8x8 block/thread, symmetric fast DCT (D half-matrix in SGPRs),
//      per-WG max -> d_ws; streams 63 AC |coeff| as packed f16 pairs (RTZ)
//      in lane-coalesced dword stores (bag layout -- k2 ignores order).
//      Slot 64 = f16 -inf pad. First 24 WGs zero d_out.
//  k2: uint4 mag loads (L2/L3-hot), reduces 1536 partial maxima, bins 64
//      halves/thread gated on >=0 (pad reject), 16-replica LDS atomic hist,
//      64 exact dyadic float atomicAdds per WG.
// Fallback (ws too small): recompute-DCT histogram kernel.

#define NUM_BINS 64
#define HREP 16
#define NWG1 1536                 // 393216 blocks / 256 threads
#define MAGS_OFF 8192             // bytes into d_ws where mags start

typedef unsigned int uint;
typedef __fp16 fp16x2 __attribute__((ext_vector_type(2)));

__device__ __forceinline__ void load_block(const float* __restrict__ p, float* blk) {
    #pragma unroll
    for (int r = 0; r < 8; ++r) {
        float4 a = *reinterpret_cast<const float4*>(p + (size_t)r * 512);
        float4 b = *reinterpret_cast<const float4*>(p + (size_t)r * 512 + 4);
        blk[r*8+0]=a.x; blk[r*8+1]=a.y; blk[r*8+2]=a.z; blk[r*8+3]=a.w;
        blk[r*8+4]=b.x; blk[r*8+5]=b.y; blk[r*8+6]=b.z; blk[r*8+7]=b.w;
    }
}

// Symmetric 2D DCT. Dh[r*4+c] = basis[r*8+c] (left half; rows obey
// D[i][7-j] = (-1)^i D[i][j]). blk butterflied in place. Emits 63 AC |coeff|.
template <typename F>
__device__ __forceinline__ float dct_block_sym(const float* Dh, float* blk, F&& emit) {
    #pragma unroll
    for (int j = 0; j < 4; ++j)
        #pragma unroll
        for (int k = 0; k < 8; ++k) {
            float a = blk[j*8+k], b = blk[(7-j)*8+k];
            blk[j*8+k]     = a + b;
            blk[(7-j)*8+k] = a - b;
        }

    float m = 0.0f;
    #pragma unroll
    for (int i = 0; i < 8; ++i) {
        float u[8];
        #pragma unroll
        for (int k = 0; k < 8; ++k) {
            float s = 0.0f;
            #pragma unroll
            for (int j = 0; j < 4; ++j) {
                int row = (i & 1) ? (7 - j) : j;     // compile-time constant
                s = fmaf(Dh[i*4+j], blk[row*8+k], s);
            }
            u[k] = s;
        }
        #pragma unroll
        for (int l = 0; l < 4; ++l) {
            float e = 0.0f, o = 0.0f;
            #pragma unroll
            for (int k = 0; k < 4; ++k) {
                e = fmaf(u[2*k],   Dh[(2*k)*4+l],   e);
                o = fmaf(u[2*k+1], Dh[(2*k+1)*4+l], o);
            }
            float v0 = e + o;          // coeff (i, l)
            float v1 = e - o;          // coeff (i, 7-l)
            float m1 = fabsf(v1);
            m = fmaxf(m, m1);
            emit(m1);
            if (i != 0 || l != 0) {    // drop DC only
                float m0 = fabsf(v0);
                m = fmaxf(m, m0);
                emit(m0);
            }
        }
    }
    return m;
}

struct NoEmit { __device__ void operator()(float) const {} };

__device__ __forceinline__ float wave_then_wg_max(float m, float* wred) {
    #pragma unroll
    for (int off = 32; off > 0; off >>= 1)
        m = fmaxf(m, __shfl_down(m, off, 64));
    if ((threadIdx.x & 63) == 0) wred[threadIdx.x >> 6] = m;
    __syncthreads();
    return fmaxf(fmaxf(wred[0], wred[1]), fmaxf(wred[2], wred[3]));
}

// ---------------- Pass 1: max + stream packed f16 mags --------
template <bool WRITE_MAGS>
__global__ __launch_bounds__(256) void dct_max_kernel(
    const float* __restrict__ x, const float* __restrict__ basis,
    float* __restrict__ wgmax, uint* __restrict__ mags, float* __restrict__ out)
{
    __shared__ float wred[4];
    float Dh[32];
    #pragma unroll
    for (int r = 0; r < 8; ++r)
        #pragma unroll
        for (int c = 0; c < 4; ++c)
            Dh[r*4+c] = basis[r*8+c];     // uniform const index -> s_load

    if (blockIdx.x < 24) out[blockIdx.x * 256 + threadIdx.x] = 0.0f;

    int tid = blockIdx.x * 256 + threadIdx.x;   // one 8x8 block per thread
    int bc  = tid >> 12, n = tid & 4095;
    const float* p = x + ((size_t)bc << 18) + ((size_t)((n >> 6) * 8) << 9)
                       + (size_t)((n & 63) * 8);
    float blk[64];
    load_block(p, blk);

    float m;
    if (WRITE_MAGS) {
        // bag layout: wave w owns dwords [w*2048, (w+1)*2048); pair q of
        // lane l at w*2048 + q*64 + l -> each store instruction covers 64
        // consecutive dwords (256B contiguous per wave): fully coalesced.
        uint* wbase = mags + (size_t)(tid >> 6) * 2048 + (tid & 63);
        float flo = 0.0f;
        int   e   = 0;
        m = dct_block_sym(Dh, blk, [&](float mag) {
            if ((e & 1) == 0) flo = mag;
            else {
                fp16x2 h2 = __builtin_amdgcn_cvt_pkrtz(flo, mag);
                wbase[(e >> 1) * 64] = __builtin_bit_cast(uint, h2);
            }
            ++e;                                   // fully unrolled: e is const
        });
        // 63 emits -> last pair: (emit#62, -inf pad)
        fp16x2 h2 = __builtin_amdgcn_cvt_pkrtz(flo, -__builtin_inff());
        wbase[31 * 64] = __builtin_bit_cast(uint, h2);
    } else {
        m = dct_block_sym(Dh, blk, NoEmit{});
    }

    float wm = wave_then_wg_max(m, wred);
    if (threadIdx.x == 0) wgmax[blockIdx.x] = wm;
}

__device__ __forceinline__ float reduce_scale(const float* __restrict__ wgmax,
                                              float* wred, float* s_scale) {
    float m = 0.0f;
    for (int i = threadIdx.x; i < NWG1; i += 256) m = fmaxf(m, wgmax[i]);
    float wm = wave_then_wg_max(m, wred);
    if (threadIdx.x == 0) *s_scale = (float)NUM_BINS / (wm * 1.1f);
    __syncthreads();
    return *s_scale;
}

// ---------------- Pass 2: histogram from packed f16 mags ----------------
__global__ __launch_bounds__(256) void dct_hist_frommags(
    const uint* __restrict__ mags, const float* __restrict__ wgmax,
    float* __restrict__ out)
{
    __shared__ uint hist[NUM_BINS * HREP];   // 4 KiB
    __shared__ float wred[4];
    __shared__ float s_scale;
    for (int i = threadIdx.x; i < NUM_BINS * HREP; i += 256) hist[i] = 0;

    float scale = reduce_scale(wgmax, wred, &s_scale);
    int   sub   = threadIdx.x & (HREP - 1);
    int   bc    = blockIdx.x >> 4;            // 16 WGs per (b,c)

    // this WG consumes dwords [blockIdx.x*8192, +8192): 8 coalesced uint4 loads
    const uint* src = mags + (size_t)blockIdx.x * 8192 + threadIdx.x * 4;
    #pragma unroll
    for (int j = 0; j < 8; ++j) {
        uint4 v = *reinterpret_cast<const uint4*>(src + (size_t)j * 1024);
        uint w[4] = {v.x, v.y, v.z, v.w};
        #pragma unroll
        for (int u = 0; u < 4; ++u) {
            fp16x2 h2 = __builtin_bit_cast(fp16x2, w[u]);
            float f0 = (float)h2[0];
            float f1 = (float)h2[1];
            // pad = -inf: gate on >= 0 (all real mags are >= 0)
            int b0 = min((int)(fmaxf(f0, 0.0f) * scale), NUM_BINS - 1);
            int b1 = min((int)(fmaxf(f1, 0.0f) * scale), NUM_BINS - 1);
            if (f0 >= 0.0f) atomicAdd(&hist[b0 * HREP + sub], 1u);
            if (f1 >= 0.0f) atomicAdd(&hist[b1 * HREP + sub], 1u);
        }
    }
    __syncthreads();

    if (threadIdx.x < NUM_BINS) {
        uint c = 0;
        #pragma unroll
        for (int r = 0; r < HREP; ++r) c += hist[threadIdx.x * HREP + r];
        // counts <= 2^18, /2^18 dyadic -> float atomic sum exact + deterministic
        atomicAdd(&out[bc * NUM_BINS + threadIdx.x], (float)c * (1.0f / 262144.0f));
    }
}

// ---------------- Fallback pass 2: recompute DCT ----------------
__global__ __launch_bounds__(256) void dct_hist_recompute(
    const float* __restrict__ x, const float* __restrict__ basis,
    const float* __restrict__ wgmax, float* __restrict__ out)
{
    __shared__ uint hist[NUM_BINS * HREP];
    __shared__ float wred[4];
    __shared__ float s_scale;
    float Dh[32];
    #pragma unroll
    for (int r = 0; r < 8; ++r)
        #pragma unroll
        for (int c = 0; c < 4; ++c)
            Dh[r*4+c] = basis[r*8+c];
    for (int i = threadIdx.x; i < NUM_BINS * HREP; i += 256) hist[i] = 0;

    float scale = reduce_scale(wgmax, wred, &s_scale);
    int   sub   = threadIdx.x & (HREP - 1);
    int   bc    = blockIdx.x >> 4;
    int   n     = (blockIdx.x & 15) * 256 + threadIdx.x;
    const float* p = x + ((size_t)bc << 18) + ((size_t)((n >> 6) * 8) << 9)
                       + (size_t)((n & 63) * 8);
    float blk[64];
    load_block(p, blk);
    dct_block_sym(Dh, blk, [&](float mag) {
        int bin = min((int)(mag * scale), NUM_BINS - 1);
        atomicAdd(&hist[bin * HREP + sub], 1u);
    });
    __syncthreads();

    if (threadIdx.x < NUM_BINS) {
        uint c = 0;
        #pragma unroll
        for (int r = 0; r < HREP; ++r) c += hist[threadIdx.x * HREP + r];
        atomicAdd(&out[bc * NUM_BINS + threadIdx.x], (float)c * (1.0f / 262144.0f));
    }
}

extern "C" void kernel_launch(void* const* d_in, const int* in_sizes, int n_in,
                              void* d_out, int out_size, void* d_ws, size_t ws_size,
                              hipStream_t stream) {
    const float* x     = (const float*)d_in[0];
    const float* basis = (const float*)d_in[1];
    float* out         = (float*)d_out;
    float* wgmax       = (float*)d_ws;
    uint*  mags        = (uint*)((char*)d_ws + MAGS_OFF);

    const size_t need = (size_t)MAGS_OFF + (size_t)NWG1 * 256 * 128;  // 50.34 MB
    if (ws_size >= need) {
        dct_max_kernel<true><<<NWG1, 256, 0, stream>>>(x, basis, wgmax, mags, out);
        dct_hist_frommags<<<NWG1, 256, 0, stream>>>(mags, wgmax, out);
    } else {
        dct_max_kernel<false><<<NWG1, 256, 0, stream>>>(x, basis, wgmax, mags, out);
        dct_hist_recompute<<<NWG1, 256, 0, stream>>>(x, basis, wgmax, out);
    }
}